// Round 4
// baseline (29966.910 us; speedup 1.0000x reference)
//
#include <hip/hip_runtime.h>

typedef unsigned long long u64;

#define SEG_N     8192
#define NSEG      2
#define M_PER_SEG 2048
#define M_TOTAL   4096
#define CFEAT     64
#define COUT      128
#define NSAMPLE   16
#define DPAIRS    34          // 67 dims padded to 68 (pad dim = 0)

#define FPS_WGS_PER_SEG 16
#define FPS_PTS_PER_WG  512
#define FPS_THREADS     256
#define FPS_SLOTS       64    // 16 WGs x 4 waves, per segment
#define FPS_GRID        256   // 1 block/CU (LDS-forced) => all co-resident
#define QOFF      (DPAIRS * FPS_PTS_PER_WG * 2)
#define FPS_QBUF_FL 72
#define FPS_LDS_BYTES ((QOFF + 4 * FPS_QBUF_FL) * (int)sizeof(float))  // 140416

// d_out layout (floats): new_xyz | new_feat | new_offset | new_vel
#define OUT_XYZ   0
#define OUT_FEAT  12288
#define OUT_OFF   536576
#define OUT_VEL   536578

// d_ws layout (bytes)
#define WS_CANDA  0           // u64 candA[2][2][64] : L2-mode slots + self-test
#define WS_CANDB  2048        // u64 candB[2][2][64] : MALL-fallback slots
#define WS_CTRL   4096        // int ctrl[16]
#define WS_XCD    4160        // int xcdof[256]
#define WS_ROLE   5184        // int rolev[256]
#define WS_ZERO   6208        // memset span
#define WS_FPS    6272        // int fps_idx[2][2048]
#define WS_KNN    22656       // int knn[4096][16]

#define C_NREG  0
#define C_NDONE 1
#define C_READY 2
#define C_GFAIL 3
#define C_TDONE 4
#define C_ABORT 5
#define C_SDONE 6

#define AG  __HIP_MEMORY_SCOPE_AGENT
#define RLX __ATOMIC_RELAXED
#define ACQ __ATOMIC_ACQUIRE
#define REL __ATOMIC_RELEASE

#define T_NDONE 200000ULL     // 2 ms @ 100 MHz realtime clock
#define T_READY 500000ULL     // 5 ms
#define T_TEST  200000ULL     // 2 ms
#define MAIN_POLL_CAP (1u<<20)
#define TEST_POLL_CAP (1u<<14)

// sc0 = coherent flag (old GLC): load bypasses L1 and reads the XCD's L2;
// store writes through to it. Valid ONLY when all communicating WGs share one
// XCD -- which is verified at runtime by the self-test below.
__device__ __forceinline__ void st_slot(u64* p, u64 v) {
  asm volatile("global_store_dwordx2 %0, %1, off sc0"
               :: "v"(p), "v"(v) : "memory");
}
__device__ __forceinline__ u64 ld_slot(const u64* p) {
  u64 v;
  asm volatile("global_load_dwordx2 %0, %1, off sc0\n\ts_waitcnt vmcnt(0)"
               : "=v"(v) : "v"(p) : "memory");
  return v;
}
__device__ __forceinline__ void pub(u64* p, u64 v, int l2) {
  if (l2) st_slot(p, v);
  else    __hip_atomic_store(p, v, RLX, AG);
}
__device__ __forceinline__ u64 pol(const u64* p, int l2) {
  if (l2) return ld_slot(p);
  return __hip_atomic_load(p, RLX, AG);
}

// ---------------------------------------------------------------------------
// FPS with verified XCD-local sync and MALL fallback. See file-top theory.
// ---------------------------------------------------------------------------
__global__ __launch_bounds__(FPS_THREADS)
void fps_kernel(const float* __restrict__ xyz, const float* __restrict__ feat,
                u64* __restrict__ candA, u64* __restrict__ candB,
                int* __restrict__ ctrl, int* __restrict__ xcdof,
                int* __restrict__ rolev, int* __restrict__ fps_idx)
{
#pragma clang fp contract(off)
  extern __shared__ float ldsx[];  // [DPAIRS][512][2] then qbuf[4][72]
  __shared__ int sh_g, sh_role, sh_mode;

  const int tid  = threadIdx.x;
  const int lane = tid & 63;
  const int wv   = tid >> 6;

  // ---------- phase 0: registration (device-scope, reliable) ----------
  if (tid == 0) {
    unsigned xcd = 0;
    asm volatile("s_getreg_b32 %0, hwreg(HW_REG_XCC_ID)" : "=s"(xcd));
    int g = __hip_atomic_fetch_add(&ctrl[C_NREG], 1, RLX, AG);
    if (g < FPS_GRID)
      __hip_atomic_store(&xcdof[g], (int)((xcd & 7u) + 1u), RLX, AG);
    __hip_atomic_fetch_add(&ctrl[C_NDONE], 1, REL, AG);
    sh_g = g;
  }
  __syncthreads();
  const int g = sh_g;

  // ---------- coordinator: block of rank 0, whole-WG parallel ----------
  if (g == 0) {
    int* carr = (int*)ldsx;            // reuse big LDS before staging
    int* rbuf = carr + FPS_GRID;
    int* hist = rbuf + FPS_GRID;
    if (tid < 8) hist[tid] = 0;
    if (tid == 0) {
      u64 t0 = __builtin_amdgcn_s_memrealtime();
      for (;;) {
        int nd = __hip_atomic_load(&ctrl[C_NDONE], ACQ, AG);
        if (nd >= FPS_GRID - 16) break;
        if (__builtin_amdgcn_s_memrealtime() - t0 > T_NDONE) break;
        __builtin_amdgcn_s_sleep(8);
      }
    }
    __syncthreads();
    int v = __hip_atomic_load(&xcdof[tid], RLX, AG);
    carr[tid] = v;
    if (v) atomicAdd(&hist[(v - 1) & 7], 1);
    __syncthreads();
    if (tid == 0) {
      int x0 = 0; for (int i = 1; i < 8; i++) if (hist[i] > hist[x0]) x0 = i;
      int x1 = (x0 == 0) ? 1 : 0;
      for (int i = 0; i < 8; i++) if (i != x0 && hist[i] > hist[x1]) x1 = i;
      int l2 = 0, both = 0;
      if (hist[x0] >= 16 && hist[x1] >= 16)      { l2 = 1; both = 0; }
      else if (hist[x0] >= 32)                   { l2 = 1; both = 1; }
      int t0c = 0, t1c = 0;
      for (int b = 0; b < FPS_GRID; b++) {
        int vv = carr[b], role = 0;
        if (vv) {
          int x = (vv - 1) & 7;
          if (l2) {
            if (both) {
              if (x == x0) {
                if (t0c < 16)      role = 0x40 | 0x20 | 0 | (t0c++ << 1);
                else if (t1c < 16) role = 0x40 | 0x20 | 1 | (t1c++ << 1);
              }
            } else {
              if (x == x0 && t0c < 16)      role = 0x40 | 0x20 | 0 | (t0c++ << 1);
              else if (x == x1 && t1c < 16) role = 0x40 | 0x20 | 1 | (t1c++ << 1);
            }
          } else {
            if (t0c < 16)      role = 0x40 | 0 | (t0c++ << 1);
            else if (t1c < 16) role = 0x40 | 1 | (t1c++ << 1);
          }
        }
        rbuf[b] = role;
      }
      if (t0c < 16 || t1c < 16)
        __hip_atomic_store(&ctrl[C_ABORT], 1, RLX, AG);
    }
    __syncthreads();
    __hip_atomic_store(&rolev[tid], rbuf[tid], RLX, AG);
    __hip_atomic_fetch_add(&ctrl[C_SDONE], 1, REL, AG);
    if (tid == 0) {
      u64 tt = __builtin_amdgcn_s_memrealtime();
      while (__hip_atomic_load(&ctrl[C_SDONE], ACQ, AG) < FPS_THREADS) {
        if (__builtin_amdgcn_s_memrealtime() - tt > T_NDONE) break;
      }
      __hip_atomic_store(&ctrl[C_READY], 1, REL, AG);
    }
  }

  // ---------- all blocks: fetch role (capped wait, abort-aware) ----------
  if (tid == 0) {
    u64 tt = __builtin_amdgcn_s_memrealtime();
    while (!__hip_atomic_load(&ctrl[C_READY], ACQ, AG)) {
      if (__builtin_amdgcn_s_memrealtime() - tt > T_READY) break;
      __builtin_amdgcn_s_sleep(8);
    }
    int r = __hip_atomic_load(&rolev[g], RLX, AG);
    if (__hip_atomic_load(&ctrl[C_ABORT], RLX, AG)) r = 0;
    sh_role = r;
  }
  __syncthreads();
  const int role = sh_role;
  if (!(role & 0x40)) return;                   // not a worker
  const int s = role & 1, wg = (role >> 1) & 15, tryl2 = (role >> 5) & 1;

  // ---------- phase 1: sc0 coherence self-test + device-scope consensus ----
  if (tid == 0) sh_mode = 0;
  __syncthreads();
  if (tryl2) {
    if (wv == 0) {
      int fail = 0;
      u64* rowA = candA + (0 * NSEG + s) * FPS_SLOTS;
      for (int r = 1; r <= 2; ++r) {
        if (lane == 0)
          st_slot(&rowA[wg * 4], ((u64)(0x10000u + (unsigned)r) << 45) | (u64)wg);
        if (lane < 16) {
          unsigned it = 0;
          for (;;) {
            u64 vv = ld_slot(&rowA[lane * 4]);
            if ((unsigned)(vv >> 45) == 0x10000u + (unsigned)r) break;
            if (++it > TEST_POLL_CAP) { fail = 1; break; }
            __builtin_amdgcn_s_sleep(1);
          }
        }
        fail = (__ballot(fail) != 0ULL) ? 1 : 0;
      }
      if (lane == 0) {
        __hip_atomic_fetch_or(&ctrl[C_GFAIL], fail, RLX, AG);
        __hip_atomic_fetch_add(&ctrl[C_TDONE], 1, REL, AG);
        u64 tt = __builtin_amdgcn_s_memrealtime();
        int ok = 0;
        for (;;) {
          if (__hip_atomic_load(&ctrl[C_TDONE], ACQ, AG) >= NSEG * FPS_WGS_PER_SEG) { ok = 1; break; }
          if (__builtin_amdgcn_s_memrealtime() - tt > T_TEST) break;
          __builtin_amdgcn_s_sleep(2);
        }
        int gf = __hip_atomic_load(&ctrl[C_GFAIL], RLX, AG);
        sh_mode = (ok && !gf && !fail) ? 1 : 0;
      }
    }
    __syncthreads();
  }
  const int mode = sh_mode;                     // 1 = XCD-local sc0, 0 = MALL
  u64* cb = mode ? candA : candB;               // distinct region per mode

  // ---------- staging: 512 points x 68 dims, transposed pair-major ----------
  const int pbase = wg * FPS_PTS_PER_WG;
  const int grow  = s * SEG_N + pbase;
  float* qbw = ldsx + QOFF + wv * FPS_QBUF_FL;

  for (int e = tid; e < FPS_PTS_PER_WG * 64; e += FPS_THREADS) {
    int p = e >> 6, c = e & 63;
    int d = 3 + c;
    ldsx[((d >> 1) * FPS_PTS_PER_WG + p) * 2 + (d & 1)] =
        feat[(size_t)(grow + p) * CFEAT + c];
  }
  for (int e = tid; e < FPS_PTS_PER_WG * 3; e += FPS_THREADS) {
    int p = e / 3, d = e - p * 3;
    ldsx[((d >> 1) * FPS_PTS_PER_WG + p) * 2 + (d & 1)] =
        xyz[(size_t)(grow + p) * 3 + d];
  }
  for (int p = tid; p < FPS_PTS_PER_WG; p += FPS_THREADS)
    ldsx[(33 * FPS_PTS_PER_WG + p) * 2 + 1] = 0.f;

  {  // q for step 1 = segment point 0 (each wave fills its own copy)
    size_t qb = (size_t)(s * SEG_N);
    float qv = (lane < 3) ? xyz[qb * 3 + lane] : feat[qb * CFEAT + (lane - 3)];
    qbw[lane] = qv;
    if (lane < 4) qbw[64 + lane] = (lane < 3) ? feat[qb * CFEAT + 61 + lane] : 0.f;
  }
  if (tid == 0 && wg == 0) fps_idx[s * M_PER_SEG] = 0;
  __syncthreads();

  float D0 = 1e10f, D1 = 1e10f;
  const float4* xp  = (const float4*)ldsx;
  const float2* q2p = (const float2*)qbw;

  for (int t = 1; t < M_PER_SEG; ++t) {
    float r0[8] = {0,0,0,0,0,0,0,0};
    float r1[8] = {0,0,0,0,0,0,0,0};
    #pragma unroll
    for (int dp = 0; dp < DPAIRS; ++dp) {
      float4 v = xp[dp * 256 + tid];
      float2 q = q2p[dp];
      float t00 = v.x - q.x, t01 = v.y - q.y;
      float t10 = v.z - q.x, t11 = v.w - q.y;
      float s00 = t00 * t00, s01 = t01 * t01;
      float s10 = t10 * t10, s11 = t11 * t11;
      r0[(2*dp) & 7]     += s00;
      r0[(2*dp + 1) & 7] += s01;
      r1[(2*dp) & 7]     += s10;
      r1[(2*dp + 1) & 7] += s11;
    }
    float a0 = ((r0[0]+r0[1])+(r0[2]+r0[3])) + ((r0[4]+r0[5])+(r0[6]+r0[7]));
    float a1 = ((r1[0]+r1[1])+(r1[2]+r1[3])) + ((r1[4]+r1[5])+(r1[6]+r1[7]));
    D0 = fminf(D0, a0);
    D1 = fminf(D1, a1);

    float bd; int bi;
    if (D1 > D0) { bd = D1; bi = pbase + 2*tid + 1; }
    else         { bd = D0; bi = pbase + 2*tid;     }
    #pragma unroll
    for (int off = 32; off >= 1; off >>= 1) {
      float od = __shfl_xor(bd, off);
      int   oi = __shfl_xor(bi, off);
      if (od > bd || (od == bd && oi < bi)) { bd = od; bi = oi; }
    }

    u64* base = &cb[(((unsigned)t & 1u) * NSEG + s) * FPS_SLOTS];
    if (lane == 0) {
      u64 pack = ((u64)(unsigned)t << 45)
               | ((u64)__float_as_uint(bd) << 13)
               | (u64)(unsigned)(8191 - bi);
      pub(&base[wg * 4 + wv], pack, mode);
    }

    // every wave polls all 64 slots (one per lane); capped + abort-safe
    u64 v = pol(&base[lane], mode);
    unsigned it = 0;
    while ((unsigned)(v >> 45) != (unsigned)t) {
      if ((++it & 2047u) == 0u) {
        if (it > MAIN_POLL_CAP || __hip_atomic_load(&ctrl[C_ABORT], RLX, AG)) {
          if (lane == 0) __hip_atomic_store(&ctrl[C_ABORT], 1, RLX, AG);
          break;
        }
      }
      __builtin_amdgcn_s_sleep(1);
      v = pol(&base[lane], mode);
    }
    #pragma unroll
    for (int off = 32; off >= 1; off >>= 1) {
      u64 o = __shfl_xor(v, off);
      if (o > v) v = o;
    }
    int qi = 8191 - (int)(v & 0x1FFFu);
    if (wg == 0 && wv == 0 && lane == 0) fps_idx[s * M_PER_SEG + t] = qi;

    size_t qb = (size_t)(s * SEG_N + qi);
    float qv = (lane < 3) ? xyz[qb * 3 + lane] : feat[qb * CFEAT + (lane - 3)];
    qbw[lane] = qv;
    if (lane < 4) qbw[64 + lane] = (lane < 3) ? feat[qb * CFEAT + 61 + lane] : 0.f;
    asm volatile("s_waitcnt lgkmcnt(0)" ::: "memory");
  }
}

// ---------------------------------------------------------------------------
__global__ void gather_kernel(const float* __restrict__ xyz, const float* __restrict__ vel,
                              const int* __restrict__ fps_idx, float* __restrict__ out)
{
  int i = blockIdx.x * 256 + threadIdx.x;
  if (i >= M_TOTAL) return;
  int s = i >> 11, r = i & 2047;
  int g = s * SEG_N + (fps_idx[s * M_PER_SEG + r] & 8191);  // mask: no OOB ever
  out[OUT_XYZ + i*3 + 0] = xyz[(size_t)g*3 + 0];
  out[OUT_XYZ + i*3 + 1] = xyz[(size_t)g*3 + 1];
  out[OUT_XYZ + i*3 + 2] = xyz[(size_t)g*3 + 2];
  out[OUT_VEL + i*3 + 0] = vel[(size_t)g*3 + 0];
  out[OUT_VEL + i*3 + 1] = vel[(size_t)g*3 + 1];
  out[OUT_VEL + i*3 + 2] = vel[(size_t)g*3 + 2];
  if (i == 0) { out[OUT_OFF] = 2048.0f; out[OUT_OFF + 1] = 4096.0f; }
}

// ---------------------------------------------------------------------------
#define KNN_TILE 1024
__global__ __launch_bounds__(256)
void knn_kernel(const float* __restrict__ xyz, const float* __restrict__ out,
                int* __restrict__ knn)
{
  __shared__ float px[KNN_TILE], py[KNN_TILE], pz[KNN_TILE];
  __shared__ float ldK[16][16][16];
  __shared__ float Tq[16];
  __shared__ float dbuf[16][24];
  __shared__ int   cbuf[16][24];
  __shared__ int   cnt[16];

  const int tid = threadIdx.x;
  const int ql = tid >> 4, j = tid & 15;
  const int qg = blockIdx.x * 16 + ql;
  const int s  = qg >> 11;
  const float qx = out[OUT_XYZ + qg*3 + 0];
  const float qy = out[OUT_XYZ + qg*3 + 1];
  const float qz = out[OUT_XYZ + qg*3 + 2];
  const float sq = qx*qx + qy*qy + qz*qz;

  float K[16];
  #pragma unroll
  for (int r = 0; r < 16; ++r) K[r] = 3.4e38f;

  for (int tile = 0; tile < SEG_N / KNN_TILE; ++tile) {
    __syncthreads();
    for (int u = tid; u < KNN_TILE; u += 256) {
      size_t g = (size_t)(s * SEG_N + tile * KNN_TILE + u);
      px[u] = xyz[g*3+0]; py[u] = xyz[g*3+1]; pz[u] = xyz[g*3+2];
    }
    __syncthreads();
    #pragma unroll 4
    for (int i = 0; i < KNN_TILE / 16; ++i) {
      int c = i * 16 + j;
      float x = px[c], y = py[c], z = pz[c];
      float sp  = x*x + y*y + z*z;
      float dot = qx*x + qy*y + qz*z;
      float d2  = (sq + sp) - 2.0f * dot;
      #pragma unroll
      for (int r = 15; r >= 1; --r)
        K[r] = fminf(fmaxf(d2, K[r-1]), K[r]);
      K[0] = fminf(K[0], d2);
    }
  }
  #pragma unroll
  for (int r = 0; r < 16; ++r) ldK[ql][j][r] = K[r];
  __syncthreads();

  {
    int head = 0;
    float T = 3.4e38f;
    for (int r = 0; r < 16; ++r) {
      float val = (head < 16) ? ldK[ql][j][head] : 3.4e38f;
      float mv = val; int ml = j;
      #pragma unroll
      for (int off = 8; off >= 1; off >>= 1) {
        float ov = __shfl_xor(mv, off, 16);
        int   ol = __shfl_xor(ml, off, 16);
        if (ov < mv || (ov == mv && ol < ml)) { mv = ov; ml = ol; }
      }
      if (j == ml) head++;
      T = mv;
    }
    if (j == 0) { Tq[ql] = T; cnt[ql] = 0; }
  }
  __syncthreads();
  const float T  = Tq[ql];
  const float Tm = T + fabsf(T) * 1e-6f + 1e-30f;

  for (int tile = 0; tile < SEG_N / KNN_TILE; ++tile) {
    __syncthreads();
    for (int u = tid; u < KNN_TILE; u += 256) {
      size_t g = (size_t)(s * SEG_N + tile * KNN_TILE + u);
      px[u] = xyz[g*3+0]; py[u] = xyz[g*3+1]; pz[u] = xyz[g*3+2];
    }
    __syncthreads();
    for (int i = 0; i < KNN_TILE / 16; ++i) {
      int c = i * 16 + j;
      float x = px[c], y = py[c], z = pz[c];
      float sp  = x*x + y*y + z*z;
      float dot = qx*x + qy*y + qz*z;
      float d2  = (sq + sp) - 2.0f * dot;
      if (d2 <= Tm) {
        int pos = atomicAdd(&cnt[ql], 1);
        if (pos < 24) { dbuf[ql][pos] = d2; cbuf[ql][pos] = tile * KNN_TILE + c; }
      }
    }
  }
  __syncthreads();

  if (j == 0) {
    int n = cnt[ql]; if (n > 24) n = 24;
    for (int r = 0; r < NSAMPLE; ++r) {
      float bv = 3.4e38f; int bc = 0, bp = -1;
      for (int e = 0; e < n; ++e) {
        float dv = dbuf[ql][e]; int cc = cbuf[ql][e];
        if (dv < bv || (dv == bv && cc < bc)) { bv = dv; bc = cc; bp = e; }
      }
      if (bp >= 0) dbuf[ql][bp] = 3.4e38f;
      knn[qg * NSAMPLE + r] = bc;
    }
  }
}

// ---------------------------------------------------------------------------
__global__ __launch_bounds__(128)
void gemm_kernel(const float* __restrict__ feat, const float* __restrict__ W,
                 const int* __restrict__ knn, float* __restrict__ out)
{
  __shared__ __align__(16) float f[NSAMPLE][CFEAT];
  __shared__ int kid[NSAMPLE];
  const int tid = threadIdx.x;
  const int q = blockIdx.x;
  const int s = q >> 11;
  if (tid < NSAMPLE) kid[tid] = knn[q * NSAMPLE + tid] & 8191;  // mask: no OOB
  __syncthreads();
  for (int e = tid; e < NSAMPLE * CFEAT; e += 128) {
    int k = e >> 6, c = e & 63;
    f[k][c] = feat[(size_t)(s * SEG_N + kid[k]) * CFEAT + c];
  }
  float4 w[16];
  const float4* Wrow = (const float4*)(W + (size_t)tid * CFEAT);
  #pragma unroll
  for (int c4 = 0; c4 < 16; ++c4) w[c4] = Wrow[c4];
  __syncthreads();

  float m = -3.4e38f;
  #pragma unroll
  for (int k = 0; k < NSAMPLE; ++k) {
    float acc = 0.f;
    const float4* frow = (const float4*)&f[k][0];
    #pragma unroll
    for (int c4 = 0; c4 < 16; ++c4) {
      float4 fv = frow[c4];
      acc += fv.x * w[c4].x + fv.y * w[c4].y + fv.z * w[c4].z + fv.w * w[c4].w;
    }
    m = fmaxf(m, acc);
  }
  out[OUT_FEAT + (size_t)q * COUT + tid] = fmaxf(m, 0.f);
}

// ---------------------------------------------------------------------------
extern "C" void kernel_launch(void* const* d_in, const int* in_sizes, int n_in,
                              void* d_out, int out_size, void* d_ws, size_t ws_size,
                              hipStream_t stream)
{
  const float* xyz  = (const float*)d_in[0];
  const float* feat = (const float*)d_in[1];
  const float* vel  = (const float*)d_in[3];
  const float* W    = (const float*)d_in[4];
  float* out = (float*)d_out;
  char*  ws  = (char*)d_ws;
  u64* candA   = (u64*)(ws + WS_CANDA);
  u64* candB   = (u64*)(ws + WS_CANDB);
  int* ctrl    = (int*)(ws + WS_CTRL);
  int* xcdof   = (int*)(ws + WS_XCD);
  int* rolev   = (int*)(ws + WS_ROLE);
  int* fps_idx = (int*)(ws + WS_FPS);
  int* knn     = (int*)(ws + WS_KNN);

  // slots + control + registration arrays must start clean every launch
  hipMemsetAsync(ws, 0, WS_ZERO, stream);

  (void)hipFuncSetAttribute((const void*)fps_kernel,
                            hipFuncAttributeMaxDynamicSharedMemorySize,
                            FPS_LDS_BYTES);
  fps_kernel<<<FPS_GRID, FPS_THREADS, FPS_LDS_BYTES, stream>>>(
      xyz, feat, candA, candB, ctrl, xcdof, rolev, fps_idx);
  gather_kernel<<<M_TOTAL / 256, 256, 0, stream>>>(xyz, vel, fps_idx, out);
  knn_kernel<<<M_TOTAL / 16, 256, 0, stream>>>(xyz, out, knn);
  gemm_kernel<<<M_TOTAL, 128, 0, stream>>>(feat, W, knn, out);
}

// Round 5
// 7786.778 us; speedup vs baseline: 3.8484x; 3.8484x over previous
//
#include <hip/hip_runtime.h>

typedef unsigned long long u64;

#define SEG_N     8192
#define NSEG      2
#define M_PER_SEG 2048
#define M_TOTAL   4096
#define CFEAT     64
#define COUT      128
#define NSAMPLE   16
#define DPAIRS    34          // 67 dims padded to 68 (pad dim = 0)

#define FPS_WGS_PER_SEG 16
#define FPS_PTS_PER_WG  512
#define FPS_THREADS     256
#define FPS_SLOTS       64    // 16 WGs x 4 waves, per segment
#define QOFF      (DPAIRS * FPS_PTS_PER_WG * 2)     // float offset of qbuf
#define FPS_LDS_BYTES ((QOFF + 72) * (int)sizeof(float))  // 139552

// d_out layout (floats): new_xyz | new_feat | new_offset | new_vel
#define OUT_XYZ   0
#define OUT_FEAT  12288      // 4096*3
#define OUT_OFF   536576     // + 4096*128
#define OUT_VEL   536578     // + 2

// d_ws layout (bytes)
#define WS_CAND 0            // u64 cand[2][2][64]  (parity, seg, wg*4+wave) = 2048 B
#define WS_FPS  2048         // int fps_idx[2][2048]
#define WS_KNN  18432        // int knn[4096][16]

#define AG  __HIP_MEMORY_SCOPE_AGENT
#define RLX __ATOMIC_RELAXED

// ---------------------------------------------------------------------------
// FPS: 16 WGs per segment, each owns 512 points LDS-resident (transposed,
// dim-pair major). Per step: min-dist update + per-wave shfl argmax; each
// wave's lane 0 publishes its step-tagged packed candidate IMMEDIATELY
// (RELAXED agent atomic -- tag+payload share one 8B word; parity double
// buffer makes slot reuse safe; poll-exit control dependency bounds skew to
// one step). Wave 0 alone polls all 64 slots (one per lane), butterfly-
// reduces the winner, reloads q's 67 coords from read-only global (L2/MALL
// hot), writes the shared qbuf. ONE barrier per step.
// ---------------------------------------------------------------------------
__global__ __launch_bounds__(FPS_THREADS)
void fps_kernel(const float* __restrict__ xyz, const float* __restrict__ feat,
                u64* __restrict__ cand, int* __restrict__ fps_idx)
{
#pragma clang fp contract(off)
  extern __shared__ float ldsx[];  // [DPAIRS][512][2] then qbuf[72]
  float* qbuf = ldsx + QOFF;

  const int tid  = threadIdx.x;
  const int lane = tid & 63;
  const int wv   = tid >> 6;
  const int s    = blockIdx.x >> 4;
  const int wg   = blockIdx.x & 15;
  const int pbase = wg * FPS_PTS_PER_WG;
  const int grow  = s * SEG_N + pbase;

  // stage feat dims 3..66 (global-coalesced reads)
  for (int e = tid; e < FPS_PTS_PER_WG * 64; e += FPS_THREADS) {
    int p = e >> 6, c = e & 63;
    int d = 3 + c;
    ldsx[((d >> 1) * FPS_PTS_PER_WG + p) * 2 + (d & 1)] =
        feat[(size_t)(grow + p) * CFEAT + c];
  }
  // xyz dims 0..2
  for (int e = tid; e < FPS_PTS_PER_WG * 3; e += FPS_THREADS) {
    int p = e / 3, d = e - p * 3;
    ldsx[((d >> 1) * FPS_PTS_PER_WG + p) * 2 + (d & 1)] =
        xyz[(size_t)(grow + p) * 3 + d];
  }
  // pad dim 67 = 0
  for (int p = tid; p < FPS_PTS_PER_WG; p += FPS_THREADS)
    ldsx[(33 * FPS_PTS_PER_WG + p) * 2 + 1] = 0.f;

  // q for step 1 = segment point 0
  if (tid < 68) {
    float v = 0.f;
    if (tid < 3)       v = xyz[(size_t)(s * SEG_N) * 3 + tid];
    else if (tid < 67) v = feat[(size_t)(s * SEG_N) * CFEAT + (tid - 3)];
    qbuf[tid] = v;
  }
  if (tid == 0 && wg == 0) fps_idx[s * M_PER_SEG] = 0;
  __syncthreads();

  float D0 = 1e10f, D1 = 1e10f;
  const float4* xp  = (const float4*)ldsx;          // index: dp*256 + tid
  const float2* q2p = (const float2*)qbuf;

  for (int t = 1; t < M_PER_SEG; ++t) {
    // numpy-style pairwise sum: 8 strided accumulators, no fma contraction
    float r0[8] = {0,0,0,0,0,0,0,0};
    float r1[8] = {0,0,0,0,0,0,0,0};
    #pragma unroll
    for (int dp = 0; dp < DPAIRS; ++dp) {
      float4 v = xp[dp * 256 + tid];   // {p0.d0, p0.d1, p1.d0, p1.d1}
      float2 q = q2p[dp];
      float t00 = v.x - q.x, t01 = v.y - q.y;
      float t10 = v.z - q.x, t11 = v.w - q.y;
      float s00 = t00 * t00, s01 = t01 * t01;
      float s10 = t10 * t10, s11 = t11 * t11;
      r0[(2*dp) & 7]     += s00;
      r0[(2*dp + 1) & 7] += s01;
      r1[(2*dp) & 7]     += s10;
      r1[(2*dp + 1) & 7] += s11;
    }
    float a0 = ((r0[0]+r0[1])+(r0[2]+r0[3])) + ((r0[4]+r0[5])+(r0[6]+r0[7]));
    float a1 = ((r1[0]+r1[1])+(r1[2]+r1[3])) + ((r1[4]+r1[5])+(r1[6]+r1[7]));
    D0 = fminf(D0, a0);
    D1 = fminf(D1, a1);

    // per-wave argmax, ties -> lowest index
    float bd; int bi;
    if (D1 > D0) { bd = D1; bi = pbase + 2*tid + 1; }
    else         { bd = D0; bi = pbase + 2*tid;     }
    #pragma unroll
    for (int off = 32; off >= 1; off >>= 1) {
      float od = __shfl_xor(bd, off);
      int   oi = __shfl_xor(bi, off);
      if (od > bd || (od == bd && oi < bi)) { bd = od; bi = oi; }
    }

    // publish-at-earliest: no funnel, no barrier before the store
    u64* base = &cand[(((unsigned)t & 1u) * NSEG + s) * FPS_SLOTS];
    if (lane == 0) {
      u64 pack = ((u64)(unsigned)t << 45)
               | ((u64)__float_as_uint(bd) << 13)
               | (u64)(unsigned)(8191 - bi);
      __hip_atomic_store(&base[wg * 4 + wv], pack, RLX, AG);
    }

    if (wv == 0) {
      // wave 0 polls all 64 slots (one per lane); immediate try, then backoff
      u64 v = __hip_atomic_load(&base[lane], RLX, AG);
      while ((unsigned)(v >> 45) != (unsigned)t) {
        __builtin_amdgcn_s_sleep(2);
        v = __hip_atomic_load(&base[lane], RLX, AG);
      }
      // butterfly max over 64 lanes (tag equal; dist then low-idx monotone)
      #pragma unroll
      for (int off = 32; off >= 1; off >>= 1) {
        u64 o = __shfl_xor(v, off);
        if (o > v) v = o;
      }
      int qi = 8191 - (int)(v & 0x1FFFu);
      if (wg == 0 && lane == 0) fps_idx[s * M_PER_SEG + t] = qi;

      // reload q coords from read-only global (L2/MALL-hot) into shared qbuf
      size_t qb = (size_t)(s * SEG_N + qi);
      float qv = (lane < 3) ? xyz[qb * 3 + lane] : feat[qb * CFEAT + (lane - 3)];
      qbuf[lane] = qv;
      if (lane < 4) qbuf[64 + lane] = (lane < 3) ? feat[qb * CFEAT + 61 + lane] : 0.f;
    }
    __syncthreads();   // single barrier per step
  }
}

// ---------------------------------------------------------------------------
__global__ void gather_kernel(const float* __restrict__ xyz, const float* __restrict__ vel,
                              const int* __restrict__ fps_idx, float* __restrict__ out)
{
  int i = blockIdx.x * 256 + threadIdx.x;
  if (i >= M_TOTAL) return;
  int s = i >> 11, r = i & 2047;
  int g = s * SEG_N + (fps_idx[s * M_PER_SEG + r] & 8191);
  out[OUT_XYZ + i*3 + 0] = xyz[(size_t)g*3 + 0];
  out[OUT_XYZ + i*3 + 1] = xyz[(size_t)g*3 + 1];
  out[OUT_XYZ + i*3 + 2] = xyz[(size_t)g*3 + 2];
  out[OUT_VEL + i*3 + 0] = vel[(size_t)g*3 + 0];
  out[OUT_VEL + i*3 + 1] = vel[(size_t)g*3 + 1];
  out[OUT_VEL + i*3 + 2] = vel[(size_t)g*3 + 2];
  if (i == 0) { out[OUT_OFF] = 2048.0f; out[OUT_OFF + 1] = 4096.0f; }
}

// ---------------------------------------------------------------------------
// kNN: 16 queries/WG, 16 scanner-threads/query. Phase 1: per-thread sorted
// top-16 (med3 chain) over stride-16 candidates from LDS tiles; 16-way merge
// -> exact global 16th-smallest T. Phase 2: rescan, collect d2 <= T*(1+eps),
// pick 16 by (d2, idx).
// ---------------------------------------------------------------------------
#define KNN_TILE 1024
__global__ __launch_bounds__(256)
void knn_kernel(const float* __restrict__ xyz, const float* __restrict__ out,
                int* __restrict__ knn)
{
  __shared__ float px[KNN_TILE], py[KNN_TILE], pz[KNN_TILE];
  __shared__ float ldK[16][16][16];
  __shared__ float Tq[16];
  __shared__ float dbuf[16][24];
  __shared__ int   cbuf[16][24];
  __shared__ int   cnt[16];

  const int tid = threadIdx.x;
  const int ql = tid >> 4, j = tid & 15;
  const int qg = blockIdx.x * 16 + ql;
  const int s  = qg >> 11;
  const float qx = out[OUT_XYZ + qg*3 + 0];
  const float qy = out[OUT_XYZ + qg*3 + 1];
  const float qz = out[OUT_XYZ + qg*3 + 2];
  const float sq = qx*qx + qy*qy + qz*qz;

  float K[16];
  #pragma unroll
  for (int r = 0; r < 16; ++r) K[r] = 3.4e38f;

  for (int tile = 0; tile < SEG_N / KNN_TILE; ++tile) {
    __syncthreads();
    for (int u = tid; u < KNN_TILE; u += 256) {
      size_t g = (size_t)(s * SEG_N + tile * KNN_TILE + u);
      px[u] = xyz[g*3+0]; py[u] = xyz[g*3+1]; pz[u] = xyz[g*3+2];
    }
    __syncthreads();
    #pragma unroll 4
    for (int i = 0; i < KNN_TILE / 16; ++i) {
      int c = i * 16 + j;
      float x = px[c], y = py[c], z = pz[c];
      float sp  = x*x + y*y + z*z;
      float dot = qx*x + qy*y + qz*z;
      float d2  = (sq + sp) - 2.0f * dot;
      #pragma unroll
      for (int r = 15; r >= 1; --r)
        K[r] = fminf(fmaxf(d2, K[r-1]), K[r]);
      K[0] = fminf(K[0], d2);
    }
  }
  #pragma unroll
  for (int r = 0; r < 16; ++r) ldK[ql][j][r] = K[r];
  __syncthreads();

  {
    int head = 0;
    float T = 3.4e38f;
    for (int r = 0; r < 16; ++r) {
      float val = (head < 16) ? ldK[ql][j][head] : 3.4e38f;
      float mv = val; int ml = j;
      #pragma unroll
      for (int off = 8; off >= 1; off >>= 1) {
        float ov = __shfl_xor(mv, off, 16);
        int   ol = __shfl_xor(ml, off, 16);
        if (ov < mv || (ov == mv && ol < ml)) { mv = ov; ml = ol; }
      }
      if (j == ml) head++;
      T = mv;
    }
    if (j == 0) { Tq[ql] = T; cnt[ql] = 0; }
  }
  __syncthreads();
  const float T  = Tq[ql];
  const float Tm = T + fabsf(T) * 1e-6f + 1e-30f;

  for (int tile = 0; tile < SEG_N / KNN_TILE; ++tile) {
    __syncthreads();
    for (int u = tid; u < KNN_TILE; u += 256) {
      size_t g = (size_t)(s * SEG_N + tile * KNN_TILE + u);
      px[u] = xyz[g*3+0]; py[u] = xyz[g*3+1]; pz[u] = xyz[g*3+2];
    }
    __syncthreads();
    for (int i = 0; i < KNN_TILE / 16; ++i) {
      int c = i * 16 + j;
      float x = px[c], y = py[c], z = pz[c];
      float sp  = x*x + y*y + z*z;
      float dot = qx*x + qy*y + qz*z;
      float d2  = (sq + sp) - 2.0f * dot;
      if (d2 <= Tm) {
        int pos = atomicAdd(&cnt[ql], 1);
        if (pos < 24) { dbuf[ql][pos] = d2; cbuf[ql][pos] = tile * KNN_TILE + c; }
      }
    }
  }
  __syncthreads();

  if (j == 0) {
    int n = cnt[ql]; if (n > 24) n = 24;
    for (int r = 0; r < NSAMPLE; ++r) {
      float bv = 3.4e38f; int bc = 0, bp = -1;
      for (int e = 0; e < n; ++e) {
        float dv = dbuf[ql][e]; int cc = cbuf[ql][e];
        if (dv < bv || (dv == bv && cc < bc)) { bv = dv; bc = cc; bp = e; }
      }
      if (bp >= 0) dbuf[ql][bp] = 3.4e38f;
      knn[qg * NSAMPLE + r] = bc;
    }
  }
}

// ---------------------------------------------------------------------------
// Gather 16 neighbor feature rows, Linear(64->128) no bias, ReLU, max over k.
// ---------------------------------------------------------------------------
__global__ __launch_bounds__(128)
void gemm_kernel(const float* __restrict__ feat, const float* __restrict__ W,
                 const int* __restrict__ knn, float* __restrict__ out)
{
  __shared__ __align__(16) float f[NSAMPLE][CFEAT];
  __shared__ int kid[NSAMPLE];
  const int tid = threadIdx.x;
  const int q = blockIdx.x;
  const int s = q >> 11;
  if (tid < NSAMPLE) kid[tid] = knn[q * NSAMPLE + tid] & 8191;
  __syncthreads();
  for (int e = tid; e < NSAMPLE * CFEAT; e += 128) {
    int k = e >> 6, c = e & 63;
    f[k][c] = feat[(size_t)(s * SEG_N + kid[k]) * CFEAT + c];
  }
  float4 w[16];
  const float4* Wrow = (const float4*)(W + (size_t)tid * CFEAT);
  #pragma unroll
  for (int c4 = 0; c4 < 16; ++c4) w[c4] = Wrow[c4];
  __syncthreads();

  float m = -3.4e38f;
  #pragma unroll
  for (int k = 0; k < NSAMPLE; ++k) {
    float acc = 0.f;
    const float4* frow = (const float4*)&f[k][0];
    #pragma unroll
    for (int c4 = 0; c4 < 16; ++c4) {
      float4 fv = frow[c4];
      acc += fv.x * w[c4].x + fv.y * w[c4].y + fv.z * w[c4].z + fv.w * w[c4].w;
    }
    m = fmaxf(m, acc);
  }
  out[OUT_FEAT + (size_t)q * COUT + tid] = fmaxf(m, 0.f);
}

// ---------------------------------------------------------------------------
extern "C" void kernel_launch(void* const* d_in, const int* in_sizes, int n_in,
                              void* d_out, int out_size, void* d_ws, size_t ws_size,
                              hipStream_t stream)
{
  const float* xyz  = (const float*)d_in[0];
  const float* feat = (const float*)d_in[1];
  // d_in[2] = offset (segment sizes fixed by the problem)
  const float* vel  = (const float*)d_in[3];
  const float* W    = (const float*)d_in[4];
  float* out = (float*)d_out;
  char*  ws  = (char*)d_ws;
  u64* cand    = (u64*)(ws + WS_CAND);
  int* fps_idx = (int*)(ws + WS_FPS);
  int* knn     = (int*)(ws + WS_KNN);

  // parity-tagged candidate slots must start clean every launch
  hipMemsetAsync(cand, 0, 2048, stream);

  (void)hipFuncSetAttribute((const void*)fps_kernel,
                            hipFuncAttributeMaxDynamicSharedMemorySize,
                            FPS_LDS_BYTES);
  fps_kernel<<<NSEG * FPS_WGS_PER_SEG, FPS_THREADS, FPS_LDS_BYTES, stream>>>(
      xyz, feat, cand, fps_idx);
  gather_kernel<<<M_TOTAL / 256, 256, 0, stream>>>(xyz, vel, fps_idx, out);
  knn_kernel<<<M_TOTAL / 16, 256, 0, stream>>>(xyz, out, knn);
  gemm_kernel<<<M_TOTAL, 128, 0, stream>>>(feat, W, knn, out);
}

// Round 6
// 6449.617 us; speedup vs baseline: 4.6463x; 1.2073x over previous
//
#include <hip/hip_runtime.h>

typedef unsigned long long u64;

#define SEG_N     8192
#define NSEG      2
#define M_PER_SEG 2048
#define M_TOTAL   4096
#define CFEAT     64
#define COUT      128
#define NSAMPLE   16

#define FPS_WGS_PER_SEG 8
#define FPS_PTS_PER_WG  1024
#define FPS_THREADS     1024
#define FPS_WAVES       16
#define SLOT_STRIDE     16    // u64s per (parity,seg) row: 8 used + 8 pad (128B line)

// d_out layout (floats): new_xyz | new_feat | new_offset | new_vel
#define OUT_XYZ   0
#define OUT_FEAT  12288      // 4096*3
#define OUT_OFF   536576     // + 4096*128
#define OUT_VEL   536578     // + 2

// d_ws layout (bytes)
#define WS_CAND 0            // u64 cand[2][2][16]  (parity, seg, wg-slot row) = 512 B
#define WS_FPS  512          // int fps_idx[2][2048]
#define WS_KNN  16896        // int knn[4096][16]

#define AG  __HIP_MEMORY_SCOPE_AGENT
#define RLX __ATOMIC_RELAXED

// ---------------------------------------------------------------------------
// FPS, register-resident: 8 WGs/segment x 1024 threads; each thread owns ONE
// point entirely in VGPRs (67 floats) -> the per-step distance update is pure
// VALU, zero LDS/global traffic. Per step: 67-dim dist (numpy-pairwise-exact:
// acc[d&7], 8-way tree, contract off), fmin, 64-lane shfl argmax, per-wave
// winner -> LDS funnel (16 slots), barrier, wave 0 merges + publishes ONE
// step-tagged u64 per WG (RELAXED agent atomic, parity double-buffered),
// polls the segment's 8 slots (one 128B line, lane<8), butterfly-reduces,
// broadcasts winner via LDS, barrier; all threads reload q's row (uniform,
// cache-hot) into registers. Two light barriers, one MALL round per step.
// ---------------------------------------------------------------------------
__global__ __launch_bounds__(FPS_THREADS)
void fps_kernel(const float* __restrict__ xyz, const float* __restrict__ feat,
                u64* __restrict__ cand, int* __restrict__ fps_idx)
{
#pragma clang fp contract(off)
  __shared__ u64 wslot[FPS_WAVES];
  __shared__ int qidx_sh;

  const int tid  = threadIdx.x;
  const int lane = tid & 63;
  const int wv   = tid >> 6;
  const int s    = blockIdx.x >> 3;
  const int wg   = blockIdx.x & 7;
  const int pl   = wg * FPS_PTS_PER_WG + tid;     // segment-local point id
  const size_t gr = (size_t)(s * SEG_N + pl);     // global row

  // ---- stage my point into registers (one-time gather) ----
  float p[67];
  p[0] = xyz[gr*3+0]; p[1] = xyz[gr*3+1]; p[2] = xyz[gr*3+2];
  {
    const float4* fr = (const float4*)(feat + gr * CFEAT);
    #pragma unroll
    for (int k = 0; k < 16; ++k) {
      float4 v = fr[k];
      p[3+4*k] = v.x; p[4+4*k] = v.y; p[5+4*k] = v.z; p[6+4*k] = v.w;
    }
  }

  // ---- q for step 1 = segment point 0 (uniform row, broadcast load) ----
  float q[67];
  {
    size_t qb = (size_t)(s * SEG_N);
    q[0] = xyz[qb*3+0]; q[1] = xyz[qb*3+1]; q[2] = xyz[qb*3+2];
    const float4* frq = (const float4*)(feat + qb * CFEAT);
    #pragma unroll
    for (int k = 0; k < 16; ++k) {
      float4 v = frq[k];
      q[3+4*k] = v.x; q[4+4*k] = v.y; q[5+4*k] = v.z; q[6+4*k] = v.w;
    }
  }
  if (tid == 0 && wg == 0) fps_idx[s * M_PER_SEG] = 0;

  float D = 1e10f;

  for (int t = 1; t < M_PER_SEG; ++t) {
    // numpy-style pairwise sum: acc[d&7], ascending d, no fma contraction.
    // (pad dim 67 contributed exactly +0.0f before; skipping it is identical)
    float r[8] = {0,0,0,0,0,0,0,0};
    #pragma unroll
    for (int d = 0; d < 67; ++d) {
      float tt = p[d] - q[d];
      float ss = tt * tt;
      r[d & 7] += ss;
    }
    float a = ((r[0]+r[1])+(r[2]+r[3])) + ((r[4]+r[5])+(r[6]+r[7]));
    D = fminf(D, a);

    // 64-lane argmax, ties -> lowest index
    float bd = D; int bi = pl;
    #pragma unroll
    for (int off = 32; off >= 1; off >>= 1) {
      float od = __shfl_xor(bd, off);
      int   oi = __shfl_xor(bi, off);
      if (od > bd || (od == bd && oi < bi)) { bd = od; bi = oi; }
    }
    if (lane == 0)
      wslot[wv] = ((u64)__float_as_uint(bd) << 13) | (u64)(unsigned)(8191 - bi);
    __syncthreads();                               // funnel ready

    if (wv == 0) {
      u64 w = (lane < FPS_WAVES) ? wslot[lane] : 0ULL;
      #pragma unroll
      for (int off = 8; off >= 1; off >>= 1) {
        u64 o = __shfl_xor(w, off, 16);
        if (o > w) w = o;
      }
      u64* base = &cand[(((unsigned)t & 1u) * NSEG + s) * SLOT_STRIDE];
      if (lane == 0)
        __hip_atomic_store(&base[wg], ((u64)(unsigned)t << 45) | w, RLX, AG);

      // poll the segment's 8 WG-slots (one 128B line, one per lane<8)
      u64 v = 0;
      if (lane < FPS_WGS_PER_SEG) {
        v = __hip_atomic_load(&base[lane], RLX, AG);
        while ((unsigned)(v >> 45) != (unsigned)t) {
          __builtin_amdgcn_s_sleep(1);
          v = __hip_atomic_load(&base[lane], RLX, AG);
        }
      }
      // butterfly max (tagged winner dominates the 0-filled lanes)
      #pragma unroll
      for (int off = 32; off >= 1; off >>= 1) {
        u64 o = __shfl_xor(v, off);
        if (o > v) v = o;
      }
      int qi = 8191 - (int)(v & 0x1FFFu);
      if (lane == 0) {
        qidx_sh = qi;
        if (wg == 0) fps_idx[s * M_PER_SEG + t] = qi;
      }
    }
    __syncthreads();                               // winner broadcast

    // reload q's 67 coords (uniform row, L1/L2-hot) into registers
    {
      size_t qb = (size_t)(s * SEG_N + qidx_sh);
      q[0] = xyz[qb*3+0]; q[1] = xyz[qb*3+1]; q[2] = xyz[qb*3+2];
      const float4* frq = (const float4*)(feat + qb * CFEAT);
      #pragma unroll
      for (int k = 0; k < 16; ++k) {
        float4 v = frq[k];
        q[3+4*k] = v.x; q[4+4*k] = v.y; q[5+4*k] = v.z; q[6+4*k] = v.w;
      }
    }
  }
}

// ---------------------------------------------------------------------------
__global__ void gather_kernel(const float* __restrict__ xyz, const float* __restrict__ vel,
                              const int* __restrict__ fps_idx, float* __restrict__ out)
{
  int i = blockIdx.x * 256 + threadIdx.x;
  if (i >= M_TOTAL) return;
  int s = i >> 11, r = i & 2047;
  int g = s * SEG_N + (fps_idx[s * M_PER_SEG + r] & 8191);
  out[OUT_XYZ + i*3 + 0] = xyz[(size_t)g*3 + 0];
  out[OUT_XYZ + i*3 + 1] = xyz[(size_t)g*3 + 1];
  out[OUT_XYZ + i*3 + 2] = xyz[(size_t)g*3 + 2];
  out[OUT_VEL + i*3 + 0] = vel[(size_t)g*3 + 0];
  out[OUT_VEL + i*3 + 1] = vel[(size_t)g*3 + 1];
  out[OUT_VEL + i*3 + 2] = vel[(size_t)g*3 + 2];
  if (i == 0) { out[OUT_OFF] = 2048.0f; out[OUT_OFF + 1] = 4096.0f; }
}

// ---------------------------------------------------------------------------
// kNN: 16 queries/WG, 16 scanner-threads/query. Phase 1: per-thread sorted
// top-16 (med3 chain) over stride-16 candidates from LDS tiles; 16-way merge
// -> exact global 16th-smallest T. Phase 2: rescan, collect d2 <= T*(1+eps),
// pick 16 by (d2, idx).
// ---------------------------------------------------------------------------
#define KNN_TILE 1024
__global__ __launch_bounds__(256)
void knn_kernel(const float* __restrict__ xyz, const float* __restrict__ out,
                int* __restrict__ knn)
{
  __shared__ float px[KNN_TILE], py[KNN_TILE], pz[KNN_TILE];
  __shared__ float ldK[16][16][16];
  __shared__ float Tq[16];
  __shared__ float dbuf[16][24];
  __shared__ int   cbuf[16][24];
  __shared__ int   cnt[16];

  const int tid = threadIdx.x;
  const int ql = tid >> 4, j = tid & 15;
  const int qg = blockIdx.x * 16 + ql;
  const int s  = qg >> 11;
  const float qx = out[OUT_XYZ + qg*3 + 0];
  const float qy = out[OUT_XYZ + qg*3 + 1];
  const float qz = out[OUT_XYZ + qg*3 + 2];
  const float sq = qx*qx + qy*qy + qz*qz;

  float K[16];
  #pragma unroll
  for (int r = 0; r < 16; ++r) K[r] = 3.4e38f;

  for (int tile = 0; tile < SEG_N / KNN_TILE; ++tile) {
    __syncthreads();
    for (int u = tid; u < KNN_TILE; u += 256) {
      size_t g = (size_t)(s * SEG_N + tile * KNN_TILE + u);
      px[u] = xyz[g*3+0]; py[u] = xyz[g*3+1]; pz[u] = xyz[g*3+2];
    }
    __syncthreads();
    #pragma unroll 4
    for (int i = 0; i < KNN_TILE / 16; ++i) {
      int c = i * 16 + j;
      float x = px[c], y = py[c], z = pz[c];
      float sp  = x*x + y*y + z*z;
      float dot = qx*x + qy*y + qz*z;
      float d2  = (sq + sp) - 2.0f * dot;
      #pragma unroll
      for (int r = 15; r >= 1; --r)
        K[r] = fminf(fmaxf(d2, K[r-1]), K[r]);
      K[0] = fminf(K[0], d2);
    }
  }
  #pragma unroll
  for (int r = 0; r < 16; ++r) ldK[ql][j][r] = K[r];
  __syncthreads();

  {
    int head = 0;
    float T = 3.4e38f;
    for (int r = 0; r < 16; ++r) {
      float val = (head < 16) ? ldK[ql][j][head] : 3.4e38f;
      float mv = val; int ml = j;
      #pragma unroll
      for (int off = 8; off >= 1; off >>= 1) {
        float ov = __shfl_xor(mv, off, 16);
        int   ol = __shfl_xor(ml, off, 16);
        if (ov < mv || (ov == mv && ol < ml)) { mv = ov; ml = ol; }
      }
      if (j == ml) head++;
      T = mv;
    }
    if (j == 0) { Tq[ql] = T; cnt[ql] = 0; }
  }
  __syncthreads();
  const float T  = Tq[ql];
  const float Tm = T + fabsf(T) * 1e-6f + 1e-30f;

  for (int tile = 0; tile < SEG_N / KNN_TILE; ++tile) {
    __syncthreads();
    for (int u = tid; u < KNN_TILE; u += 256) {
      size_t g = (size_t)(s * SEG_N + tile * KNN_TILE + u);
      px[u] = xyz[g*3+0]; py[u] = xyz[g*3+1]; pz[u] = xyz[g*3+2];
    }
    __syncthreads();
    for (int i = 0; i < KNN_TILE / 16; ++i) {
      int c = i * 16 + j;
      float x = px[c], y = py[c], z = pz[c];
      float sp  = x*x + y*y + z*z;
      float dot = qx*x + qy*y + qz*z;
      float d2  = (sq + sp) - 2.0f * dot;
      if (d2 <= Tm) {
        int pos = atomicAdd(&cnt[ql], 1);
        if (pos < 24) { dbuf[ql][pos] = d2; cbuf[ql][pos] = tile * KNN_TILE + c; }
      }
    }
  }
  __syncthreads();

  if (j == 0) {
    int n = cnt[ql]; if (n > 24) n = 24;
    for (int r = 0; r < NSAMPLE; ++r) {
      float bv = 3.4e38f; int bc = 0, bp = -1;
      for (int e = 0; e < n; ++e) {
        float dv = dbuf[ql][e]; int cc = cbuf[ql][e];
        if (dv < bv || (dv == bv && cc < bc)) { bv = dv; bc = cc; bp = e; }
      }
      if (bp >= 0) dbuf[ql][bp] = 3.4e38f;
      knn[qg * NSAMPLE + r] = bc;
    }
  }
}

// ---------------------------------------------------------------------------
// Gather 16 neighbor feature rows, Linear(64->128) no bias, ReLU, max over k.
// ---------------------------------------------------------------------------
__global__ __launch_bounds__(128)
void gemm_kernel(const float* __restrict__ feat, const float* __restrict__ W,
                 const int* __restrict__ knn, float* __restrict__ out)
{
  __shared__ __align__(16) float f[NSAMPLE][CFEAT];
  __shared__ int kid[NSAMPLE];
  const int tid = threadIdx.x;
  const int q = blockIdx.x;
  const int s = q >> 11;
  if (tid < NSAMPLE) kid[tid] = knn[q * NSAMPLE + tid] & 8191;
  __syncthreads();
  for (int e = tid; e < NSAMPLE * CFEAT; e += 128) {
    int k = e >> 6, c = e & 63;
    f[k][c] = feat[(size_t)(s * SEG_N + kid[k]) * CFEAT + c];
  }
  float4 w[16];
  const float4* Wrow = (const float4*)(W + (size_t)tid * CFEAT);
  #pragma unroll
  for (int c4 = 0; c4 < 16; ++c4) w[c4] = Wrow[c4];
  __syncthreads();

  float m = -3.4e38f;
  #pragma unroll
  for (int k = 0; k < NSAMPLE; ++k) {
    float acc = 0.f;
    const float4* frow = (const float4*)&f[k][0];
    #pragma unroll
    for (int c4 = 0; c4 < 16; ++c4) {
      float4 fv = frow[c4];
      acc += fv.x * w[c4].x + fv.y * w[c4].y + fv.z * w[c4].z + fv.w * w[c4].w;
    }
    m = fmaxf(m, acc);
  }
  out[OUT_FEAT + (size_t)q * COUT + tid] = fmaxf(m, 0.f);
}

// ---------------------------------------------------------------------------
extern "C" void kernel_launch(void* const* d_in, const int* in_sizes, int n_in,
                              void* d_out, int out_size, void* d_ws, size_t ws_size,
                              hipStream_t stream)
{
  const float* xyz  = (const float*)d_in[0];
  const float* feat = (const float*)d_in[1];
  // d_in[2] = offset (segment sizes fixed by the problem)
  const float* vel  = (const float*)d_in[3];
  const float* W    = (const float*)d_in[4];
  float* out = (float*)d_out;
  char*  ws  = (char*)d_ws;
  u64* cand    = (u64*)(ws + WS_CAND);
  int* fps_idx = (int*)(ws + WS_FPS);
  int* knn     = (int*)(ws + WS_KNN);

  // step tags repeat across graph replays -> slots must start clean
  hipMemsetAsync(cand, 0, 512, stream);

  fps_kernel<<<NSEG * FPS_WGS_PER_SEG, FPS_THREADS, 0, stream>>>(
      xyz, feat, cand, fps_idx);
  gather_kernel<<<M_TOTAL / 256, 256, 0, stream>>>(xyz, vel, fps_idx, out);
  knn_kernel<<<M_TOTAL / 16, 256, 0, stream>>>(xyz, out, knn);
  gemm_kernel<<<M_TOTAL, 128, 0, stream>>>(feat, W, knn, out);
}

// Round 7
// 5013.591 us; speedup vs baseline: 5.9771x; 1.2864x over previous
//
#include <hip/hip_runtime.h>

typedef unsigned long long u64;

#define SEG_N     8192
#define NSEG      2
#define M_PER_SEG 2048
#define M_TOTAL   4096
#define CFEAT     64
#define COUT      128
#define NSAMPLE   16

#define FPS_WGS_PER_SEG 16
#define FPS_THREADS     512
#define FPS_WAVES       8
#define SLOT_STRIDE     16    // u64s per (parity,seg) row = 128B line

// d_out layout (floats): new_xyz | new_feat | new_offset | new_vel
#define OUT_XYZ   0
#define OUT_FEAT  12288      // 4096*3
#define OUT_OFF   536576     // + 4096*128
#define OUT_VEL   536578     // + 2

// d_ws layout (bytes)
#define WS_CAND 0            // u64 cand[2][2][16]  (parity, seg, wg) = 512 B
#define WS_FPS  512          // int fps_idx[2][2048]
#define WS_KNN  16896        // int knn[4096][16]

#define AG  __HIP_MEMORY_SCOPE_AGENT
#define RLX __ATOMIC_RELAXED

// ---------------------------------------------------------------------------
// FPS, register-resident (actually, this time): 16 WGs/segment x 512 threads;
// each thread owns ONE point (67 floats) AND the current query q (67 floats)
// in VGPRs -- launch_bounds(512,2) caps occupancy at 2 waves/SIMD so the
// 256-VGPR budget holds both arrays with no scratch spill; every p[]/q[]
// access sits in a fully-unrolled loop (static indices). Per step: 67-dim
// dist (numpy-pairwise-exact: acc[d&7] ascending, 8-way tree, contract off),
// fmin, 64-lane shfl argmax, 8-wave LDS funnel, barrier; wave 0 merges,
// publishes ONE step-tagged u64 per WG (RELAXED agent atomic, parity
// double-buffered), polls the segment's 16 slots (one 128B line, lane<16),
// butterfly-reduces, broadcasts winner via LDS; barrier; all threads reload
// q's row (uniform, L2-hot) into registers.
// ---------------------------------------------------------------------------
__global__ __launch_bounds__(FPS_THREADS, 2)
void fps_kernel(const float* __restrict__ xyz, const float* __restrict__ feat,
                u64* __restrict__ cand, int* __restrict__ fps_idx)
{
#pragma clang fp contract(off)
  __shared__ u64 wslot[FPS_WAVES];
  __shared__ int qidx_sh;

  const int tid  = threadIdx.x;
  const int lane = tid & 63;
  const int wv   = tid >> 6;
  const int s    = blockIdx.x >> 4;
  const int wg   = blockIdx.x & 15;
  const int pl   = wg * FPS_THREADS + tid;        // segment-local point id
  const size_t gr = (size_t)(s * SEG_N + pl);     // global row

  // ---- stage my point into registers (one-time gather) ----
  float p[67];
  p[0] = xyz[gr*3+0]; p[1] = xyz[gr*3+1]; p[2] = xyz[gr*3+2];
  {
    const float4* fr = (const float4*)(feat + gr * CFEAT);
    #pragma unroll
    for (int k = 0; k < 16; ++k) {
      float4 v = fr[k];
      p[3+4*k] = v.x; p[4+4*k] = v.y; p[5+4*k] = v.z; p[6+4*k] = v.w;
    }
  }

  // ---- q for step 1 = segment point 0 (uniform row, broadcast load) ----
  float q[67];
  {
    size_t qb = (size_t)(s * SEG_N);
    q[0] = xyz[qb*3+0]; q[1] = xyz[qb*3+1]; q[2] = xyz[qb*3+2];
    const float4* frq = (const float4*)(feat + qb * CFEAT);
    #pragma unroll
    for (int k = 0; k < 16; ++k) {
      float4 v = frq[k];
      q[3+4*k] = v.x; q[4+4*k] = v.y; q[5+4*k] = v.z; q[6+4*k] = v.w;
    }
  }
  if (tid == 0 && wg == 0) fps_idx[s * M_PER_SEG] = 0;

  float D = 1e10f;

  for (int t = 1; t < M_PER_SEG; ++t) {
    // numpy-style pairwise sum: acc[d&7], ascending d, no fma contraction
    float r[8] = {0,0,0,0,0,0,0,0};
    #pragma unroll
    for (int d = 0; d < 67; ++d) {
      float tt = p[d] - q[d];
      float ss = tt * tt;
      r[d & 7] += ss;
    }
    float a = ((r[0]+r[1])+(r[2]+r[3])) + ((r[4]+r[5])+(r[6]+r[7]));
    D = fminf(D, a);

    // 64-lane argmax, ties -> lowest index
    float bd = D; int bi = pl;
    #pragma unroll
    for (int off = 32; off >= 1; off >>= 1) {
      float od = __shfl_xor(bd, off);
      int   oi = __shfl_xor(bi, off);
      if (od > bd || (od == bd && oi < bi)) { bd = od; bi = oi; }
    }
    if (lane == 0)
      wslot[wv] = ((u64)__float_as_uint(bd) << 13) | (u64)(unsigned)(8191 - bi);
    __syncthreads();                               // funnel ready

    if (wv == 0) {
      u64 w = (lane < FPS_WAVES) ? wslot[lane] : 0ULL;
      #pragma unroll
      for (int off = 4; off >= 1; off >>= 1) {
        u64 o = __shfl_xor(w, off, 8);
        if (o > w) w = o;
      }
      u64* base = &cand[(((unsigned)t & 1u) * NSEG + s) * SLOT_STRIDE];
      if (lane == 0)
        __hip_atomic_store(&base[wg], ((u64)(unsigned)t << 45) | w, RLX, AG);

      // poll the segment's 16 WG-slots (one 128B line, one per lane<16)
      u64 v = 0;
      if (lane < FPS_WGS_PER_SEG) {
        v = __hip_atomic_load(&base[lane], RLX, AG);
        while ((unsigned)(v >> 45) != (unsigned)t) {
          __builtin_amdgcn_s_sleep(1);
          v = __hip_atomic_load(&base[lane], RLX, AG);
        }
      }
      // 16-wide butterfly max (tagged winners dominate 0-filled lanes)
      #pragma unroll
      for (int off = 8; off >= 1; off >>= 1) {
        u64 o = __shfl_xor(v, off, 16);
        if (o > v) v = o;
      }
      int qi = 8191 - (int)(v & 0x1FFFu);
      if (lane == 0) {
        qidx_sh = qi;
        if (wg == 0) fps_idx[s * M_PER_SEG + t] = qi;
      }
    }
    __syncthreads();                               // winner broadcast

    // reload q's 67 coords (uniform row, L2-hot) into registers
    {
      size_t qb = (size_t)(s * SEG_N + qidx_sh);
      q[0] = xyz[qb*3+0]; q[1] = xyz[qb*3+1]; q[2] = xyz[qb*3+2];
      const float4* frq = (const float4*)(feat + qb * CFEAT);
      #pragma unroll
      for (int k = 0; k < 16; ++k) {
        float4 v = frq[k];
        q[3+4*k] = v.x; q[4+4*k] = v.y; q[5+4*k] = v.z; q[6+4*k] = v.w;
      }
    }
  }
}

// ---------------------------------------------------------------------------
__global__ void gather_kernel(const float* __restrict__ xyz, const float* __restrict__ vel,
                              const int* __restrict__ fps_idx, float* __restrict__ out)
{
  int i = blockIdx.x * 256 + threadIdx.x;
  if (i >= M_TOTAL) return;
  int s = i >> 11, r = i & 2047;
  int g = s * SEG_N + (fps_idx[s * M_PER_SEG + r] & 8191);
  out[OUT_XYZ + i*3 + 0] = xyz[(size_t)g*3 + 0];
  out[OUT_XYZ + i*3 + 1] = xyz[(size_t)g*3 + 1];
  out[OUT_XYZ + i*3 + 2] = xyz[(size_t)g*3 + 2];
  out[OUT_VEL + i*3 + 0] = vel[(size_t)g*3 + 0];
  out[OUT_VEL + i*3 + 1] = vel[(size_t)g*3 + 1];
  out[OUT_VEL + i*3 + 2] = vel[(size_t)g*3 + 2];
  if (i == 0) { out[OUT_OFF] = 2048.0f; out[OUT_OFF + 1] = 4096.0f; }
}

// ---------------------------------------------------------------------------
// kNN: 16 queries/WG, 16 scanner-threads/query. Phase 1: per-thread sorted
// top-16 (med3 chain) over stride-16 candidates from LDS tiles; 16-way merge
// -> exact global 16th-smallest T. Phase 2: rescan, collect d2 <= T*(1+eps),
// pick 16 by (d2, idx).
// ---------------------------------------------------------------------------
#define KNN_TILE 1024
__global__ __launch_bounds__(256)
void knn_kernel(const float* __restrict__ xyz, const float* __restrict__ out,
                int* __restrict__ knn)
{
  __shared__ float px[KNN_TILE], py[KNN_TILE], pz[KNN_TILE];
  __shared__ float ldK[16][16][16];
  __shared__ float Tq[16];
  __shared__ float dbuf[16][24];
  __shared__ int   cbuf[16][24];
  __shared__ int   cnt[16];

  const int tid = threadIdx.x;
  const int ql = tid >> 4, j = tid & 15;
  const int qg = blockIdx.x * 16 + ql;
  const int s  = qg >> 11;
  const float qx = out[OUT_XYZ + qg*3 + 0];
  const float qy = out[OUT_XYZ + qg*3 + 1];
  const float qz = out[OUT_XYZ + qg*3 + 2];
  const float sq = qx*qx + qy*qy + qz*qz;

  float K[16];
  #pragma unroll
  for (int r = 0; r < 16; ++r) K[r] = 3.4e38f;

  for (int tile = 0; tile < SEG_N / KNN_TILE; ++tile) {
    __syncthreads();
    for (int u = tid; u < KNN_TILE; u += 256) {
      size_t g = (size_t)(s * SEG_N + tile * KNN_TILE + u);
      px[u] = xyz[g*3+0]; py[u] = xyz[g*3+1]; pz[u] = xyz[g*3+2];
    }
    __syncthreads();
    #pragma unroll 4
    for (int i = 0; i < KNN_TILE / 16; ++i) {
      int c = i * 16 + j;
      float x = px[c], y = py[c], z = pz[c];
      float sp  = x*x + y*y + z*z;
      float dot = qx*x + qy*y + qz*z;
      float d2  = (sq + sp) - 2.0f * dot;
      #pragma unroll
      for (int r = 15; r >= 1; --r)
        K[r] = fminf(fmaxf(d2, K[r-1]), K[r]);
      K[0] = fminf(K[0], d2);
    }
  }
  #pragma unroll
  for (int r = 0; r < 16; ++r) ldK[ql][j][r] = K[r];
  __syncthreads();

  {
    int head = 0;
    float T = 3.4e38f;
    for (int r = 0; r < 16; ++r) {
      float val = (head < 16) ? ldK[ql][j][head] : 3.4e38f;
      float mv = val; int ml = j;
      #pragma unroll
      for (int off = 8; off >= 1; off >>= 1) {
        float ov = __shfl_xor(mv, off, 16);
        int   ol = __shfl_xor(ml, off, 16);
        if (ov < mv || (ov == mv && ol < ml)) { mv = ov; ml = ol; }
      }
      if (j == ml) head++;
      T = mv;
    }
    if (j == 0) { Tq[ql] = T; cnt[ql] = 0; }
  }
  __syncthreads();
  const float T  = Tq[ql];
  const float Tm = T + fabsf(T) * 1e-6f + 1e-30f;

  for (int tile = 0; tile < SEG_N / KNN_TILE; ++tile) {
    __syncthreads();
    for (int u = tid; u < KNN_TILE; u += 256) {
      size_t g = (size_t)(s * SEG_N + tile * KNN_TILE + u);
      px[u] = xyz[g*3+0]; py[u] = xyz[g*3+1]; pz[u] = xyz[g*3+2];
    }
    __syncthreads();
    for (int i = 0; i < KNN_TILE / 16; ++i) {
      int c = i * 16 + j;
      float x = px[c], y = py[c], z = pz[c];
      float sp  = x*x + y*y + z*z;
      float dot = qx*x + qy*y + qz*z;
      float d2  = (sq + sp) - 2.0f * dot;
      if (d2 <= Tm) {
        int pos = atomicAdd(&cnt[ql], 1);
        if (pos < 24) { dbuf[ql][pos] = d2; cbuf[ql][pos] = tile * KNN_TILE + c; }
      }
    }
  }
  __syncthreads();

  if (j == 0) {
    int n = cnt[ql]; if (n > 24) n = 24;
    for (int r = 0; r < NSAMPLE; ++r) {
      float bv = 3.4e38f; int bc = 0, bp = -1;
      for (int e = 0; e < n; ++e) {
        float dv = dbuf[ql][e]; int cc = cbuf[ql][e];
        if (dv < bv || (dv == bv && cc < bc)) { bv = dv; bc = cc; bp = e; }
      }
      if (bp >= 0) dbuf[ql][bp] = 3.4e38f;
      knn[qg * NSAMPLE + r] = bc;
    }
  }
}

// ---------------------------------------------------------------------------
// Gather 16 neighbor feature rows, Linear(64->128) no bias, ReLU, max over k.
// ---------------------------------------------------------------------------
__global__ __launch_bounds__(128)
void gemm_kernel(const float* __restrict__ feat, const float* __restrict__ W,
                 const int* __restrict__ knn, float* __restrict__ out)
{
  __shared__ __align__(16) float f[NSAMPLE][CFEAT];
  __shared__ int kid[NSAMPLE];
  const int tid = threadIdx.x;
  const int q = blockIdx.x;
  const int s = q >> 11;
  if (tid < NSAMPLE) kid[tid] = knn[q * NSAMPLE + tid] & 8191;
  __syncthreads();
  for (int e = tid; e < NSAMPLE * CFEAT; e += 128) {
    int k = e >> 6, c = e & 63;
    f[k][c] = feat[(size_t)(s * SEG_N + kid[k]) * CFEAT + c];
  }
  float4 w[16];
  const float4* Wrow = (const float4*)(W + (size_t)tid * CFEAT);
  #pragma unroll
  for (int c4 = 0; c4 < 16; ++c4) w[c4] = Wrow[c4];
  __syncthreads();

  float m = -3.4e38f;
  #pragma unroll
  for (int k = 0; k < NSAMPLE; ++k) {
    float acc = 0.f;
    const float4* frow = (const float4*)&f[k][0];
    #pragma unroll
    for (int c4 = 0; c4 < 16; ++c4) {
      float4 fv = frow[c4];
      acc += fv.x * w[c4].x + fv.y * w[c4].y + fv.z * w[c4].z + fv.w * w[c4].w;
    }
    m = fmaxf(m, acc);
  }
  out[OUT_FEAT + (size_t)q * COUT + tid] = fmaxf(m, 0.f);
}

// ---------------------------------------------------------------------------
extern "C" void kernel_launch(void* const* d_in, const int* in_sizes, int n_in,
                              void* d_out, int out_size, void* d_ws, size_t ws_size,
                              hipStream_t stream)
{
  const float* xyz  = (const float*)d_in[0];
  const float* feat = (const float*)d_in[1];
  // d_in[2] = offset (segment sizes fixed by the problem)
  const float* vel  = (const float*)d_in[3];
  const float* W    = (const float*)d_in[4];
  float* out = (float*)d_out;
  char*  ws  = (char*)d_ws;
  u64* cand    = (u64*)(ws + WS_CAND);
  int* fps_idx = (int*)(ws + WS_FPS);
  int* knn     = (int*)(ws + WS_KNN);

  // step tags repeat across graph replays -> slots must start clean
  hipMemsetAsync(cand, 0, 512, stream);

  fps_kernel<<<NSEG * FPS_WGS_PER_SEG, FPS_THREADS, 0, stream>>>(
      xyz, feat, cand, fps_idx);
  gather_kernel<<<M_TOTAL / 256, 256, 0, stream>>>(xyz, vel, fps_idx, out);
  knn_kernel<<<M_TOTAL / 16, 256, 0, stream>>>(xyz, out, knn);
  gemm_kernel<<<M_TOTAL, 128, 0, stream>>>(feat, W, knn, out);
}